// Round 8
// baseline (102.779 us; speedup 1.0000x reference)
//
#include <hip/hip_runtime.h>
#include <math.h>

#define NODE_DIM 128
#define HIDDEN   64
#define NN       2048
#define LSTR     68   // floats per LDS row: 64 data + 4 pad (272 B, 16B-aligned)

typedef float v4f __attribute__((ext_vector_type(4)));

// ---------------------------------------------------------------------------
// Prep — VERBATIM from R7 (passed):
//   h = nf[r] @ W_enc + b_enc
//   A[r]  = h @ W1[:64]          (fp32)
//   BB[r] = h @ W1[64:] + b1     (b1 folded)
//   pa[r] = sum_h W2[h]*A[r,h]   pb[r] = sum_h W2[h]*BB[r,h]
// ---------------------------------------------------------------------------
__global__ __launch_bounds__(256) void prep_kernel(
    const float* __restrict__ nf, const float* __restrict__ W_enc,
    const float* __restrict__ b_enc, const float* __restrict__ W1,
    const float* __restrict__ b1, const float* __restrict__ W2,
    float* __restrict__ A, float* __restrict__ BB,
    float* __restrict__ pa, float* __restrict__ pb)
{
    __shared__ float nf_s[4][NODE_DIM];
    __shared__ float h_s[4][HIDDEN];
    __shared__ float ra_s[4][HIDDEN];
    __shared__ float rb_s[4][HIDDEN];
    const int tid = threadIdx.x;
    const int rg  = tid >> 6;
    const int t   = tid & 63;
    const int r   = blockIdx.x * 4 + rg;

    ((float2*)nf_s[rg])[t] = ((const float2*)(nf + (size_t)r * NODE_DIM))[t];
    __syncthreads();

    float acc = b_enc[t];
    #pragma unroll 8
    for (int k = 0; k < NODE_DIM; ++k)
        acc = fmaf(nf_s[rg][k], W_enc[k * HIDDEN + t], acc);
    h_s[rg][t] = acc;
    __syncthreads();

    float aacc = 0.0f;
    float bacc = b1[t];
    #pragma unroll 8
    for (int k = 0; k < HIDDEN; ++k) {
        const float hv = h_s[rg][k];
        aacc = fmaf(hv, W1[k * HIDDEN + t], aacc);
        bacc = fmaf(hv, W1[(HIDDEN + k) * HIDDEN + t], bacc);
    }
    A[(size_t)r * HIDDEN + t]  = aacc;
    BB[(size_t)r * HIDDEN + t] = bacc;

    const float wv = W2[t];
    ra_s[rg][t] = wv * aacc;
    rb_s[rg][t] = wv * bacc;
    __syncthreads();

    #pragma unroll
    for (int s = 32; s > 0; s >>= 1) {
        if (t < s) {
            ra_s[rg][t] += ra_s[rg][t + s];
            rb_s[rg][t] += rb_s[rg][t + s];
        }
        __syncthreads();
    }
    if (t == 0) { pa[r] = ra_s[rg][0]; pb[r] = rb_s[rg][0]; }
}

// ---------------------------------------------------------------------------
// Pairwise (R7-verbatim MATH — passed twice):
//   S[i][j] = sum_h W2[h] * |A[i,h] + BB[j,h]|
//   logit   = b2 + 0.5*(pa[i] + pb[j] + S[i][j])      (relu = (x+|x|)/2)
//   T[i][j] = sigmoid(logit), diagonal zeroed.
//
// R8 config change: micro-tile 4x8 -> 8x8 (i = i0+ty+16*ii, j = j0+tx+16*jj,
// ty,tx 0..15), tile 128x128, 256 threads, grid 16x16 = 256 = 1 block/CU.
// LDS traffic drops 1.5 -> 1.0 B/(output*h): per chunk per CU 64 ds_read_b128
// (768 cyc) == per-SIMD VALU 384 instr (768 cyc) — both pipes balanced and
// overlapping. Main loop is BARRIER-FREE after the single staging sync, so
// 1 wave/SIMD still pipelines (compiler lgkmcnt scheduling; chunk c+1 reads
// prefetch during chunk c compute). Guard rails vs R6: #pragma unroll 2 only
// (~210 VGPR, no spill), launch_bounds matches block size exactly.
// Banks (stride 68, start = 4*row mod 32): A-reads 4 rows/wave x 16-lane
// broadcast -> conflict-free; B-reads 16 rows, 2-way -> free.
// ---------------------------------------------------------------------------
__global__ __launch_bounds__(256, 1) void pair_kernel(
    const float* __restrict__ A, const float* __restrict__ BB,
    const float* __restrict__ pa, const float* __restrict__ pb,
    const float* __restrict__ W2, const float* __restrict__ b2,
    float* __restrict__ out)
{
    __shared__ __align__(16) float aL[128 * LSTR];   // 34.8 KB
    __shared__ __align__(16) float bL[128 * LSTR];   // 34.8 KB

    const int tid = threadIdx.x;
    const int i0  = blockIdx.y * 128;
    const int j0  = blockIdx.x * 128;

    // ---- stage: A tile 128x64 fp32 (2048 float4), B tile 128x64 (2048) ----
    const v4f* gA = (const v4f*)(A  + (size_t)i0 * HIDDEN);
    const v4f* gB = (const v4f*)(BB + (size_t)j0 * HIDDEN);
    #pragma unroll
    for (int k = 0; k < 8; ++k) {
        const int idx = tid + k * 256;   // 0..2047
        const int row = idx >> 4;        // 16 float4 per row
        const int c   = idx & 15;
        *(v4f*)&aL[row * LSTR + c * 4] = gA[idx];
        *(v4f*)&bL[row * LSTR + c * 4] = gB[idx];
    }
    __syncthreads();

    const int ty = tid >> 4;   // 0..15 : i = i0 + ty + 16*ii
    const int tx = tid & 15;   // 0..15 : j = j0 + tx + 16*jj

    float acc[8][8] = {{0.0f}};

    #pragma unroll 2
    for (int c = 0; c < 16; ++c) {       // 4 h per chunk
        const float w0 = W2[c * 4 + 0];  // uniform -> SGPR operands
        const float w1 = W2[c * 4 + 1];
        const float w2 = W2[c * 4 + 2];
        const float w3 = W2[c * 4 + 3];
        v4f av[8], bv[8];
        #pragma unroll
        for (int ii = 0; ii < 8; ++ii)
            av[ii] = *(const v4f*)&aL[(ty + 16 * ii) * LSTR + c * 4];
        #pragma unroll
        for (int jj = 0; jj < 8; ++jj)
            bv[jj] = *(const v4f*)&bL[(tx + 16 * jj) * LSTR + c * 4];
        #pragma unroll
        for (int ii = 0; ii < 8; ++ii) {
            #pragma unroll
            for (int jj = 0; jj < 8; ++jj) {
                const v4f t = av[ii] + bv[jj];   // 2x v_pk_add_f32
                float s = acc[ii][jj];
                s = fmaf(__builtin_fabsf(t[0]), w0, s);  // v_fma_f32, abs() src mod
                s = fmaf(__builtin_fabsf(t[1]), w1, s);
                s = fmaf(__builtin_fabsf(t[2]), w2, s);
                s = fmaf(__builtin_fabsf(t[3]), w3, s);
                acc[ii][jj] = s;
            }
        }
    }

    // ---- epilogue: logit = b2 + 0.5*(pa+pb+S); sigmoid; zero diag ----
    const float b2v = b2[0];
    float par[8], pbr[8];
    #pragma unroll
    for (int ii = 0; ii < 8; ++ii) par[ii] = pa[i0 + ty + 16 * ii];
    #pragma unroll
    for (int jj = 0; jj < 8; ++jj) pbr[jj] = pb[j0 + tx + 16 * jj];

    #pragma unroll
    for (int ii = 0; ii < 8; ++ii) {
        const int i = i0 + ty + 16 * ii;
        #pragma unroll
        for (int jj = 0; jj < 8; ++jj) {
            const int j = j0 + tx + 16 * jj;
            const float lg = fmaf(0.5f, par[ii] + pbr[jj] + acc[ii][jj], b2v);
            const float sg = 1.0f / (1.0f + __expf(-lg));
            out[(size_t)i * NN + j] = (i == j) ? 0.0f : sg;
        }
    }
}

extern "C" void kernel_launch(void* const* d_in, const int* in_sizes, int n_in,
                              void* d_out, int out_size, void* d_ws, size_t ws_size,
                              hipStream_t stream) {
    const float* nf    = (const float*)d_in[0];
    const float* W_enc = (const float*)d_in[1];
    const float* b_enc = (const float*)d_in[2];
    const float* W1    = (const float*)d_in[3];
    const float* b1    = (const float*)d_in[4];
    const float* W2    = (const float*)d_in[5];
    const float* b2    = (const float*)d_in[6];
    float* out = (float*)d_out;

    float* A  = (float*)d_ws;                 // 2048*64 fp32 (512 KB)
    float* BB = A + (size_t)NN * HIDDEN;      // 512 KB
    float* pa = BB + (size_t)NN * HIDDEN;     // 8 KB
    float* pb = pa + NN;                      // 8 KB

    // Block sizes match __launch_bounds__ exactly (R4 failure-mode guard):
    // prep: 256 == 256; pair: 256 == 256.
    prep_kernel<<<NN / 4, 256, 0, stream>>>(nf, W_enc, b_enc, W1, b1, W2,
                                            A, BB, pa, pb);
    pair_kernel<<<dim3(NN / 128, NN / 128), 256, 0, stream>>>(
        A, BB, pa, pb, W2, b2, out);
}

// Round 9
// 101.581 us; speedup vs baseline: 1.0118x; 1.0118x over previous
//
#include <hip/hip_runtime.h>
#include <math.h>

#define NODE_DIM 128
#define HIDDEN   64
#define NN       2048
#define LSTR     68   // floats per LDS row: 64 data + 4 pad (272 B, 16B-aligned)

typedef float v4f __attribute__((ext_vector_type(4)));

// ---------------------------------------------------------------------------
// Prep — VERBATIM from R7 (passed twice):
//   h = nf[r] @ W_enc + b_enc
//   A[r]  = h @ W1[:64]          (fp32)
//   BB[r] = h @ W1[64:] + b1     (b1 folded)
//   pa[r] = sum_h W2[h]*A[r,h]   pb[r] = sum_h W2[h]*BB[r,h]
// ---------------------------------------------------------------------------
__global__ __launch_bounds__(256) void prep_kernel(
    const float* __restrict__ nf, const float* __restrict__ W_enc,
    const float* __restrict__ b_enc, const float* __restrict__ W1,
    const float* __restrict__ b1, const float* __restrict__ W2,
    float* __restrict__ A, float* __restrict__ BB,
    float* __restrict__ pa, float* __restrict__ pb)
{
    __shared__ float nf_s[4][NODE_DIM];
    __shared__ float h_s[4][HIDDEN];
    __shared__ float ra_s[4][HIDDEN];
    __shared__ float rb_s[4][HIDDEN];
    const int tid = threadIdx.x;
    const int rg  = tid >> 6;
    const int t   = tid & 63;
    const int r   = blockIdx.x * 4 + rg;

    ((float2*)nf_s[rg])[t] = ((const float2*)(nf + (size_t)r * NODE_DIM))[t];
    __syncthreads();

    float acc = b_enc[t];
    #pragma unroll 8
    for (int k = 0; k < NODE_DIM; ++k)
        acc = fmaf(nf_s[rg][k], W_enc[k * HIDDEN + t], acc);
    h_s[rg][t] = acc;
    __syncthreads();

    float aacc = 0.0f;
    float bacc = b1[t];
    #pragma unroll 8
    for (int k = 0; k < HIDDEN; ++k) {
        const float hv = h_s[rg][k];
        aacc = fmaf(hv, W1[k * HIDDEN + t], aacc);
        bacc = fmaf(hv, W1[(HIDDEN + k) * HIDDEN + t], bacc);
    }
    A[(size_t)r * HIDDEN + t]  = aacc;
    BB[(size_t)r * HIDDEN + t] = bacc;

    const float wv = W2[t];
    ra_s[rg][t] = wv * aacc;
    rb_s[rg][t] = wv * bacc;
    __syncthreads();

    #pragma unroll
    for (int s = 32; s > 0; s >>= 1) {
        if (t < s) {
            ra_s[rg][t] += ra_s[rg][t + s];
            rb_s[rg][t] += rb_s[rg][t + s];
        }
        __syncthreads();
    }
    if (t == 0) { pa[r] = ra_s[rg][0]; pb[r] = rb_s[rg][0]; }
}

// ---------------------------------------------------------------------------
// Pairwise (R7-verbatim MATH — passed twice):
//   S[i][j] = sum_h W2[h] * |A[i,h] + BB[j,h]|
//   logit   = b2 + 0.5*(pa[i] + pb[j] + S[i][j])      (relu = (x+|x|)/2)
//   T[i][j] = sigmoid(logit), diagonal zeroed.
//
// R9 data-movement change (math untouched): A comes DIRECT from global
// (the 16 same-tx lanes read identical addresses -> coalescer dedupes to
// 4 cachelines/instr; A-tile slice 16 KB is L1-resident, A total 512 KB is
// L2-resident). Only B is staged in LDS (17.4 KB/block).
// Shape: tile 64i x 64j, 128 threads (ty=tid>>4 0..7, tx=tid&15 0..15),
// micro-tile 8i x 4j: i = i0+ty+8*ii, j = j0+tx+16*jj. Grid 32x32 = 1024
// -> 4 blocks/CU x 2 waves = 2 waves/SIMD (R8's fatal 1-wave/SIMD fixed).
// Per-CU per-chunk: VALU 768 cyc vs LDS 384 vs vmem ~320 -> VALU-bound.
// A-loads manually software-pipelined one chunk ahead (~130 VGPR, no spill).
// B-read banks: 16 rows, 4*row mod 32 -> 2-way + 4-lane broadcast -> free.
// ---------------------------------------------------------------------------
__global__ __launch_bounds__(128) void pair_kernel(
    const float* __restrict__ A, const float* __restrict__ BB,
    const float* __restrict__ pa, const float* __restrict__ pb,
    const float* __restrict__ W2, const float* __restrict__ b2,
    float* __restrict__ out)
{
    __shared__ __align__(16) float bL[64 * LSTR];   // 17.4 KB

    const int tid = threadIdx.x;
    const int i0  = blockIdx.y * 64;
    const int j0  = blockIdx.x * 64;

    // ---- stage B tile: 64 rows x 64 fp32 = 1024 float4 ----
    const v4f* gB = (const v4f*)(BB + (size_t)j0 * HIDDEN);
    #pragma unroll
    for (int k = 0; k < 8; ++k) {
        const int idx = tid + k * 128;   // 0..1023
        const int row = idx >> 4;        // 16 float4 per row
        const int c   = idx & 15;
        *(v4f*)&bL[row * LSTR + c * 4] = gB[idx];
    }
    __syncthreads();

    const int ty = tid >> 4;   // 0..7  : i = i0 + ty + 8*ii
    const int tx = tid & 15;   // 0..15 : j = j0 + tx + 16*jj

    // A row base pointers for this thread's 8 i-rows
    const float* arow[8];
    #pragma unroll
    for (int ii = 0; ii < 8; ++ii)
        arow[ii] = A + (size_t)(i0 + ty + 8 * ii) * HIDDEN;

    float acc[8][4] = {{0.0f}};

    // software pipeline: A-loads for chunk c+1 issue before chunk c compute
    v4f av[8];
    #pragma unroll
    for (int ii = 0; ii < 8; ++ii)
        av[ii] = *(const v4f*)(arow[ii] + 0);

    #pragma unroll 2
    for (int c = 0; c < 16; ++c) {       // 4 h per chunk
        v4f an[8];
        if (c < 15) {
            #pragma unroll
            for (int ii = 0; ii < 8; ++ii)
                an[ii] = *(const v4f*)(arow[ii] + (c + 1) * 4);  // prefetch
        }
        const float w0 = W2[c * 4 + 0];  // uniform -> SGPR operands
        const float w1 = W2[c * 4 + 1];
        const float w2 = W2[c * 4 + 2];
        const float w3 = W2[c * 4 + 3];
        v4f bv[4];
        #pragma unroll
        for (int jj = 0; jj < 4; ++jj)
            bv[jj] = *(const v4f*)&bL[(tx + 16 * jj) * LSTR + c * 4];
        #pragma unroll
        for (int ii = 0; ii < 8; ++ii) {
            #pragma unroll
            for (int jj = 0; jj < 4; ++jj) {
                const v4f t = av[ii] + bv[jj];   // 2x v_pk_add_f32
                float s = acc[ii][jj];
                s = fmaf(__builtin_fabsf(t[0]), w0, s);  // v_fma_f32, abs() src mod
                s = fmaf(__builtin_fabsf(t[1]), w1, s);
                s = fmaf(__builtin_fabsf(t[2]), w2, s);
                s = fmaf(__builtin_fabsf(t[3]), w3, s);
                acc[ii][jj] = s;
            }
        }
        #pragma unroll
        for (int ii = 0; ii < 8; ++ii)
            av[ii] = an[ii];
    }

    // ---- epilogue: logit = b2 + 0.5*(pa+pb+S); sigmoid; zero diag ----
    const float b2v = b2[0];
    float par[8], pbr[4];
    #pragma unroll
    for (int ii = 0; ii < 8; ++ii) par[ii] = pa[i0 + ty + 8 * ii];
    #pragma unroll
    for (int jj = 0; jj < 4; ++jj) pbr[jj] = pb[j0 + tx + 16 * jj];

    #pragma unroll
    for (int ii = 0; ii < 8; ++ii) {
        const int i = i0 + ty + 8 * ii;
        #pragma unroll
        for (int jj = 0; jj < 4; ++jj) {
            const int j = j0 + tx + 16 * jj;
            const float lg = fmaf(0.5f, par[ii] + pbr[jj] + acc[ii][jj], b2v);
            const float sg = 1.0f / (1.0f + __expf(-lg));
            out[(size_t)i * NN + j] = (i == j) ? 0.0f : sg;
        }
    }
}

extern "C" void kernel_launch(void* const* d_in, const int* in_sizes, int n_in,
                              void* d_out, int out_size, void* d_ws, size_t ws_size,
                              hipStream_t stream) {
    const float* nf    = (const float*)d_in[0];
    const float* W_enc = (const float*)d_in[1];
    const float* b_enc = (const float*)d_in[2];
    const float* W1    = (const float*)d_in[3];
    const float* b1    = (const float*)d_in[4];
    const float* W2    = (const float*)d_in[5];
    const float* b2    = (const float*)d_in[6];
    float* out = (float*)d_out;

    float* A  = (float*)d_ws;                 // 2048*64 fp32 (512 KB)
    float* BB = A + (size_t)NN * HIDDEN;      // 512 KB
    float* pa = BB + (size_t)NN * HIDDEN;     // 8 KB
    float* pb = pa + NN;                      // 8 KB

    // Block sizes match __launch_bounds__ exactly (R4 failure-mode guard):
    // prep: 256 == 256; pair: 128 == 128.
    prep_kernel<<<NN / 4, 256, 0, stream>>>(nf, W_enc, b_enc, W1, b1, W2,
                                            A, BB, pa, pb);
    pair_kernel<<<dim3(NN / 64, NN / 64), 128, 0, stream>>>(
        A, BB, pa, pb, W2, b2, out);
}

// Round 11
// 101.369 us; speedup vs baseline: 1.0139x; 1.0021x over previous
//
#include <hip/hip_runtime.h>
#include <math.h>

#define NODE_DIM 128
#define HIDDEN   64
#define NN       2048
#define USTR     36   // uints per LDS tile row: 32 (64 bf16) + 4 pad = 144 B, 16B-aligned

typedef float v4f __attribute__((ext_vector_type(4)));
typedef unsigned int uint;
typedef unsigned short ushort;
typedef uint v4u __attribute__((ext_vector_type(4)));

// fp32 -> bf16 with round-to-nearest-even (exact, well-known bit recipe)
__device__ __forceinline__ ushort f2bf(float x) {
    uint u = __builtin_bit_cast(uint, x);
    u += 0x7FFFu + ((u >> 16) & 1u);
    return (ushort)(u >> 16);
}
// bf16 pair (one uint) -> 2 exact fp32 values
__device__ __forceinline__ float bf_lo(uint u) {
    return __builtin_bit_cast(float, u << 16);
}
__device__ __forceinline__ float bf_hi(uint u) {
    return __builtin_bit_cast(float, u & 0xFFFF0000u);
}

// ---------------------------------------------------------------------------
// Prep — R7-proven structure; stores bf16 tiles; pa/pb computed from the
// ROUNDED values so the abs-identity in pair is self-consistent:
//   h = nf[r] @ W_enc + b_enc
//   Ab[r]  = bf16( h @ W1[:64] )
//   Bb[r]  = bf16( h @ W1[64:] + b1 )
//   pa[r]  = sum_h W2[h]*fp32(Ab[r,h]),  pb[r] = sum_h W2[h]*fp32(Bb[r,h])
// ---------------------------------------------------------------------------
__global__ __launch_bounds__(256) void prep_kernel(
    const float* __restrict__ nf, const float* __restrict__ W_enc,
    const float* __restrict__ b_enc, const float* __restrict__ W1,
    const float* __restrict__ b1, const float* __restrict__ W2,
    ushort* __restrict__ Ab, ushort* __restrict__ Bb,
    float* __restrict__ pa, float* __restrict__ pb)
{
    __shared__ float nf_s[4][NODE_DIM];
    __shared__ float h_s[4][HIDDEN];
    __shared__ float ra_s[4][HIDDEN];
    __shared__ float rb_s[4][HIDDEN];
    const int tid = threadIdx.x;
    const int rg  = tid >> 6;
    const int t   = tid & 63;
    const int r   = blockIdx.x * 4 + rg;

    ((float2*)nf_s[rg])[t] = ((const float2*)(nf + (size_t)r * NODE_DIM))[t];
    __syncthreads();

    float acc = b_enc[t];
    #pragma unroll 8
    for (int k = 0; k < NODE_DIM; ++k)
        acc = fmaf(nf_s[rg][k], W_enc[k * HIDDEN + t], acc);
    h_s[rg][t] = acc;
    __syncthreads();

    float aacc = 0.0f;
    float bacc = b1[t];
    #pragma unroll 8
    for (int k = 0; k < HIDDEN; ++k) {
        const float hv = h_s[rg][k];
        aacc = fmaf(hv, W1[k * HIDDEN + t], aacc);
        bacc = fmaf(hv, W1[(HIDDEN + k) * HIDDEN + t], bacc);
    }
    const ushort ua = f2bf(aacc);
    const ushort ub = f2bf(bacc);
    Ab[(size_t)r * HIDDEN + t] = ua;
    Bb[(size_t)r * HIDDEN + t] = ub;

    const float wv = W2[t];
    ra_s[rg][t] = wv * __builtin_bit_cast(float, (uint)ua << 16);
    rb_s[rg][t] = wv * __builtin_bit_cast(float, (uint)ub << 16);
    __syncthreads();

    #pragma unroll
    for (int s = 32; s > 0; s >>= 1) {
        if (t < s) {
            ra_s[rg][t] += ra_s[rg][t + s];
            rb_s[rg][t] += rb_s[rg][t + s];
        }
        __syncthreads();
    }
    if (t == 0) { pa[r] = ra_s[rg][0]; pb[r] = rb_s[rg][0]; }
}

// ---------------------------------------------------------------------------
// Pairwise — R7's PROVEN fp32 math, bf16-staged tiles (exact unpack):
//   S[i][j] = sum_h W2[h] * |a_ih + b_jh|      (a,b = bf16-rounded values)
//   logit   = b2 + 0.5*(pa[i] + pb[j] + S)     (relu = (x+|x|)/2)
//   T[i][j] = sigmoid(logit), diag 0.
// Scaffold identical to R7: 256 thr, tile 128i x 64j, grid 32x16 = 512
// (2 blocks/CU, LDS 27.7 KB x2 -> 2 waves/SIMD), micro 4i x 8j:
// i = i0+ty+32*ii (ty 0..31), j = j0+tx+8*jj (tx 0..7), unroll 2,
// bounds(256,2). Chunk = 8 h = one ds_read_b128 per row operand:
// 12 b128/thread/chunk = 0.75 B/(out*h) -> LDS 3.9 us (was 7.7 fp32).
// VALU/chunk: 96 exact unpacks (lshl/and) + 384 core (v4f add -> 2x
// v_pk_add_f32; fma with free abs() src mod) = 1.875 instr/h -> 6.4 us.
// Banks (start = 4*row mod 32): A 8 rows {0,4..28} x 8-lane bcast free;
// B 8 rows {0,4..28} x 8-lane bcast free.
// ---------------------------------------------------------------------------
__global__ __launch_bounds__(256, 2) void pair_kernel(
    const ushort* __restrict__ Ab, const ushort* __restrict__ Bb,
    const float* __restrict__ pa, const float* __restrict__ pb,
    const float* __restrict__ W2, const float* __restrict__ b2,
    float* __restrict__ out)
{
    __shared__ __align__(16) uint aHu[128 * USTR];   // 18.4 KB
    __shared__ __align__(16) uint bHu[64 * USTR];    //  9.2 KB

    const int tid = threadIdx.x;
    const int i0  = blockIdx.y * 128;
    const int j0  = blockIdx.x * 64;

    // ---- stage: A tile 128 x 64 bf16 (1024 v4u), B tile 64 x 64 (512) ----
    const v4u* gA = (const v4u*)(Ab + (size_t)i0 * HIDDEN);
    const v4u* gB = (const v4u*)(Bb + (size_t)j0 * HIDDEN);
    #pragma unroll
    for (int k = 0; k < 4; ++k) {
        const int idx = tid + k * 256;   // 0..1023
        const int row = idx >> 3;        // 8 v4u per 64-bf16 row
        const int c   = idx & 7;
        *(v4u*)&aHu[row * USTR + c * 4] = gA[idx];
    }
    #pragma unroll
    for (int k = 0; k < 2; ++k) {
        const int idx = tid + k * 256;   // 0..511
        const int row = idx >> 3;
        const int c   = idx & 7;
        *(v4u*)&bHu[row * USTR + c * 4] = gB[idx];
    }
    __syncthreads();

    const int ty = tid >> 3;   // 0..31 : i = i0 + ty + 32*ii
    const int tx = tid & 7;    // 0..7  : j = j0 + tx + 8*jj

    float acc[4][8] = {{0.0f}};

    #pragma unroll 2
    for (int c = 0; c < 8; ++c) {        // 8 h per chunk (one b128 per row)
        // SGPR weights for h = 8c .. 8c+7
        const float w0 = W2[c * 8 + 0];
        const float w1 = W2[c * 8 + 1];
        const float w2 = W2[c * 8 + 2];
        const float w3 = W2[c * 8 + 3];
        const float w4 = W2[c * 8 + 4];
        const float w5 = W2[c * 8 + 5];
        const float w6 = W2[c * 8 + 6];
        const float w7 = W2[c * 8 + 7];

        v4u au[4], bu[8];
        #pragma unroll
        for (int ii = 0; ii < 4; ++ii)
            au[ii] = *(const v4u*)&aHu[(ty + 32 * ii) * USTR + c * 4];
        #pragma unroll
        for (int jj = 0; jj < 8; ++jj)
            bu[jj] = *(const v4u*)&bHu[(tx + 8 * jj) * USTR + c * 4];

        // exact unpack bf16 -> fp32 (bit moves only)
        v4f alo[4], ahi[4], blo[8], bhi[8];
        #pragma unroll
        for (int ii = 0; ii < 4; ++ii) {
            alo[ii] = (v4f){bf_lo(au[ii][0]), bf_hi(au[ii][0]),
                            bf_lo(au[ii][1]), bf_hi(au[ii][1])};   // h 8c..8c+3
            ahi[ii] = (v4f){bf_lo(au[ii][2]), bf_hi(au[ii][2]),
                            bf_lo(au[ii][3]), bf_hi(au[ii][3])};   // h 8c+4..+7
        }
        #pragma unroll
        for (int jj = 0; jj < 8; ++jj) {
            blo[jj] = (v4f){bf_lo(bu[jj][0]), bf_hi(bu[jj][0]),
                            bf_lo(bu[jj][1]), bf_hi(bu[jj][1])};
            bhi[jj] = (v4f){bf_lo(bu[jj][2]), bf_hi(bu[jj][2]),
                            bf_lo(bu[jj][3]), bf_hi(bu[jj][3])};
        }

        #pragma unroll
        for (int ii = 0; ii < 4; ++ii) {
            #pragma unroll
            for (int jj = 0; jj < 8; ++jj) {
                float s = acc[ii][jj];
                const v4f t0 = alo[ii] + blo[jj];   // 2x v_pk_add_f32
                s = fmaf(__builtin_fabsf(t0[0]), w0, s);
                s = fmaf(__builtin_fabsf(t0[1]), w1, s);
                s = fmaf(__builtin_fabsf(t0[2]), w2, s);
                s = fmaf(__builtin_fabsf(t0[3]), w3, s);
                const v4f t1 = ahi[ii] + bhi[jj];   // 2x v_pk_add_f32
                s = fmaf(__builtin_fabsf(t1[0]), w4, s);
                s = fmaf(__builtin_fabsf(t1[1]), w5, s);
                s = fmaf(__builtin_fabsf(t1[2]), w6, s);
                s = fmaf(__builtin_fabsf(t1[3]), w7, s);
                acc[ii][jj] = s;
            }
        }
    }

    // ---- epilogue: logit = b2 + 0.5*(pa+pb+S); sigmoid; zero diag ----
    const float b2v = b2[0];
    float par[4], pbr[8];
    #pragma unroll
    for (int ii = 0; ii < 4; ++ii) par[ii] = pa[i0 + ty + 32 * ii];
    #pragma unroll
    for (int jj = 0; jj < 8; ++jj) pbr[jj] = pb[j0 + tx + 8 * jj];

    #pragma unroll
    for (int ii = 0; ii < 4; ++ii) {
        const int i = i0 + ty + 32 * ii;
        #pragma unroll
        for (int jj = 0; jj < 8; ++jj) {
            const int j = j0 + tx + 8 * jj;
            const float lg = fmaf(0.5f, par[ii] + pbr[jj] + acc[ii][jj], b2v);
            const float sg = 1.0f / (1.0f + __expf(-lg));
            out[(size_t)i * NN + j] = (i == j) ? 0.0f : sg;
        }
    }
}

extern "C" void kernel_launch(void* const* d_in, const int* in_sizes, int n_in,
                              void* d_out, int out_size, void* d_ws, size_t ws_size,
                              hipStream_t stream) {
    const float* nf    = (const float*)d_in[0];
    const float* W_enc = (const float*)d_in[1];
    const float* b_enc = (const float*)d_in[2];
    const float* W1    = (const float*)d_in[3];
    const float* b1    = (const float*)d_in[4];
    const float* W2    = (const float*)d_in[5];
    const float* b2    = (const float*)d_in[6];
    float* out = (float*)d_out;

    ushort* Ab = (ushort*)d_ws;                      // 2048*64 bf16 (256 KB)
    ushort* Bb = Ab + (size_t)NN * HIDDEN;           // 256 KB
    float*  pa = (float*)(Bb + (size_t)NN * HIDDEN); // 8 KB
    float*  pb = pa + NN;                            // 8 KB

    // Block sizes match __launch_bounds__ exactly (R4 failure-mode guard):
    // prep: 256 == 256; pair: 256 == 256.
    prep_kernel<<<NN / 4, 256, 0, stream>>>(nf, W_enc, b_enc, W1, b1, W2,
                                            Ab, Bb, pa, pb);
    pair_kernel<<<dim3(NN / 64, NN / 128), 256, 0, stream>>>(
        Ab, Bb, pa, pb, W2, b2, out);
}

// Round 12
// 100.374 us; speedup vs baseline: 1.0240x; 1.0099x over previous
//
#include <hip/hip_runtime.h>
#include <math.h>

#define NODE_DIM 128
#define HIDDEN   64
#define NN       2048
#define LSTR     68   // floats per LDS tile row: 64 data + 4 pad (272 B, 16B-aligned)

typedef float v4f __attribute__((ext_vector_type(4)));

// ---------------------------------------------------------------------------
// Prep — VERBATIM from R7 (passed 3x):
//   h = nf[r] @ W_enc + b_enc
//   A[r]  = h @ W1[:64]          (fp32)
//   BB[r] = h @ W1[64:] + b1     (b1 folded)
//   pa[r] = sum_h W2[h]*A[r,h]   pb[r] = sum_h W2[h]*BB[r,h]
// ---------------------------------------------------------------------------
__global__ __launch_bounds__(256) void prep_kernel(
    const float* __restrict__ nf, const float* __restrict__ W_enc,
    const float* __restrict__ b_enc, const float* __restrict__ W1,
    const float* __restrict__ b1, const float* __restrict__ W2,
    float* __restrict__ A, float* __restrict__ BB,
    float* __restrict__ pa, float* __restrict__ pb)
{
    __shared__ float nf_s[4][NODE_DIM];
    __shared__ float h_s[4][HIDDEN];
    __shared__ float ra_s[4][HIDDEN];
    __shared__ float rb_s[4][HIDDEN];
    const int tid = threadIdx.x;
    const int rg  = tid >> 6;
    const int t   = tid & 63;
    const int r   = blockIdx.x * 4 + rg;

    ((float2*)nf_s[rg])[t] = ((const float2*)(nf + (size_t)r * NODE_DIM))[t];
    __syncthreads();

    float acc = b_enc[t];
    #pragma unroll 8
    for (int k = 0; k < NODE_DIM; ++k)
        acc = fmaf(nf_s[rg][k], W_enc[k * HIDDEN + t], acc);
    h_s[rg][t] = acc;
    __syncthreads();

    float aacc = 0.0f;
    float bacc = b1[t];
    #pragma unroll 8
    for (int k = 0; k < HIDDEN; ++k) {
        const float hv = h_s[rg][k];
        aacc = fmaf(hv, W1[k * HIDDEN + t], aacc);
        bacc = fmaf(hv, W1[(HIDDEN + k) * HIDDEN + t], bacc);
    }
    A[(size_t)r * HIDDEN + t]  = aacc;
    BB[(size_t)r * HIDDEN + t] = bacc;

    const float wv = W2[t];
    ra_s[rg][t] = wv * aacc;
    rb_s[rg][t] = wv * bacc;
    __syncthreads();

    #pragma unroll
    for (int s = 32; s > 0; s >>= 1) {
        if (t < s) {
            ra_s[rg][t] += ra_s[rg][t + s];
            rb_s[rg][t] += rb_s[rg][t + s];
        }
        __syncthreads();
    }
    if (t == 0) { pa[r] = ra_s[rg][0]; pb[r] = rb_s[rg][0]; }
}

// ---------------------------------------------------------------------------
// Pairwise (R7's PROVEN fp32 abs-identity math, untouched):
//   S[i][j] = sum_h W2[h] * |A[i,h] + BB[j,h]|
//   logit   = b2 + 0.5*(pa[i] + pb[j] + S);  T = sigmoid(logit), diag 0.
//
// R12 config: IN-BLOCK SPLIT-K. Tile 128i x 128j, 512 threads, grid 16x16
// = 256 blocks (1 block/CU, LDS 69.6 KB). Waves 0-3 (half=0) accumulate
// h=0..31; waves 4-7 (half=1) h=32..63 — same 8x8 micro-tile per thread
// (i = i0+ty+16*ii, j = j0+tx+16*jj; ty,tx 0..15) -> LDS traffic stays at
// the optimal 1.0 B/(out*h) (R8) while occupancy is 2 waves/SIMD (R7),
// fixing R8's 1-wave/SIMD stall. Partials merge via LDS (tile buffer
// reused after barrier; [slot][thread] layout -> conflict-free; all
// half-branches wave-uniform; acc indices compile-time). Per-CU per-chunk:
// LDS 16 b128 x 512 thr ~ VALU 384 instr x 8 waves -> both ~5.1 us total,
// overlapped. Banks: A 4 rows x 16-bcast free; B 16 rows 2-way free.
// ---------------------------------------------------------------------------
__global__ __launch_bounds__(512, 2) void pair_kernel(
    const float* __restrict__ A, const float* __restrict__ BB,
    const float* __restrict__ pa, const float* __restrict__ pb,
    const float* __restrict__ W2, const float* __restrict__ b2,
    float* __restrict__ out)
{
    __shared__ __align__(16) float smem[2 * 128 * LSTR];  // 69,632 B
    float* aL = smem;               // [128][LSTR]
    float* bL = smem + 128 * LSTR;  // [128][LSTR]

    const int tid = threadIdx.x;
    const int i0  = blockIdx.y * 128;
    const int j0  = blockIdx.x * 128;

    // ---- stage: A and B tiles, 128 rows x 64 fp32 = 2048 float4 each ----
    const v4f* gA = (const v4f*)(A  + (size_t)i0 * HIDDEN);
    const v4f* gB = (const v4f*)(BB + (size_t)j0 * HIDDEN);
    #pragma unroll
    for (int k = 0; k < 4; ++k) {
        const int idx = tid + k * 512;   // 0..2047
        const int row = idx >> 4;        // 16 float4 per row
        const int c   = idx & 15;
        *(v4f*)&aL[row * LSTR + c * 4] = gA[idx];
        *(v4f*)&bL[row * LSTR + c * 4] = gB[idx];
    }
    __syncthreads();

    const int half = tid >> 8;   // 0: h=0..31, 1: h=32..63 (wave-uniform)
    const int t    = tid & 255;
    const int ty   = t >> 4;     // 0..15 : i = i0 + ty + 16*ii
    const int tx   = t & 15;     // 0..15 : j = j0 + tx + 16*jj
    const int hb   = half * 8;   // first 4h-chunk of this half

    float acc[8][8] = {{0.0f}};

    #pragma unroll 2
    for (int cc = 0; cc < 8; ++cc) {     // 8 chunks x 4 h = 32 h per half
        const int c = hb + cc;
        const float w0 = W2[c * 4 + 0];
        const float w1 = W2[c * 4 + 1];
        const float w2 = W2[c * 4 + 2];
        const float w3 = W2[c * 4 + 3];
        v4f av[8], bv[8];
        #pragma unroll
        for (int ii = 0; ii < 8; ++ii)
            av[ii] = *(const v4f*)&aL[(ty + 16 * ii) * LSTR + c * 4];
        #pragma unroll
        for (int jj = 0; jj < 8; ++jj)
            bv[jj] = *(const v4f*)&bL[(tx + 16 * jj) * LSTR + c * 4];
        #pragma unroll
        for (int ii = 0; ii < 8; ++ii) {
            #pragma unroll
            for (int jj = 0; jj < 8; ++jj) {
                const v4f tv = av[ii] + bv[jj];   // 2x v_pk_add_f32
                float s = acc[ii][jj];
                s = fmaf(__builtin_fabsf(tv[0]), w0, s);  // v_fma_f32, abs() mod
                s = fmaf(__builtin_fabsf(tv[1]), w1, s);
                s = fmaf(__builtin_fabsf(tv[2]), w2, s);
                s = fmaf(__builtin_fabsf(tv[3]), w3, s);
                acc[ii][jj] = s;
            }
        }
    }

    // ---- combine halves through LDS (tile buffers dead now) ----
    __syncthreads();                       // all tile reads complete
    float* cbuf = smem;                    // [64 slots][256 threads] = 64 KB

    // half 0 finalizes slots 0..31, half 1 finalizes slots 32..63;
    // each half writes the partials the OTHER half needs. Wave-uniform
    // branches; all acc indices compile-time constants.
    if (half == 0) {
        #pragma unroll
        for (int s = 0; s < 32; ++s) {     // write slots 32..63
            const int slot = 32 + s;
            cbuf[slot * 256 + t] = acc[slot >> 3][slot & 7];
        }
    } else {
        #pragma unroll
        for (int s = 0; s < 32; ++s) {     // write slots 0..31
            cbuf[s * 256 + t] = acc[s >> 3][s & 7];
        }
    }
    __syncthreads();

    const float b2v = b2[0];
    if (half == 0) {
        #pragma unroll
        for (int s = 0; s < 32; ++s) {     // finalize slots 0..31
            const int ii = s >> 3, jj = s & 7;
            const int i = i0 + ty + 16 * ii;
            const int j = j0 + tx + 16 * jj;
            const float S = acc[ii][jj] + cbuf[s * 256 + t];
            const float lg = fmaf(0.5f, pa[i] + pb[j] + S, b2v);
            const float sg = 1.0f / (1.0f + __expf(-lg));
            out[(size_t)i * NN + j] = (i == j) ? 0.0f : sg;
        }
    } else {
        #pragma unroll
        for (int s = 0; s < 32; ++s) {     // finalize slots 32..63
            const int slot = 32 + s;
            const int ii = slot >> 3, jj = slot & 7;
            const int i = i0 + ty + 16 * ii;
            const int j = j0 + tx + 16 * jj;
            const float S = acc[ii][jj] + cbuf[slot * 256 + t];
            const float lg = fmaf(0.5f, pa[i] + pb[j] + S, b2v);
            const float sg = 1.0f / (1.0f + __expf(-lg));
            out[(size_t)i * NN + j] = (i == j) ? 0.0f : sg;
        }
    }
}

extern "C" void kernel_launch(void* const* d_in, const int* in_sizes, int n_in,
                              void* d_out, int out_size, void* d_ws, size_t ws_size,
                              hipStream_t stream) {
    const float* nf    = (const float*)d_in[0];
    const float* W_enc = (const float*)d_in[1];
    const float* b_enc = (const float*)d_in[2];
    const float* W1    = (const float*)d_in[3];
    const float* b1    = (const float*)d_in[4];
    const float* W2    = (const float*)d_in[5];
    const float* b2    = (const float*)d_in[6];
    float* out = (float*)d_out;

    float* A  = (float*)d_ws;                 // 2048*64 fp32 (512 KB)
    float* BB = A + (size_t)NN * HIDDEN;      // 512 KB
    float* pa = BB + (size_t)NN * HIDDEN;     // 8 KB
    float* pb = pa + NN;                      // 8 KB

    // Block sizes match __launch_bounds__ exactly (R4 failure-mode guard):
    // prep: 256 == 256; pair: 512 == 512.
    prep_kernel<<<NN / 4, 256, 0, stream>>>(nf, W_enc, b_enc, W1, b1, W2,
                                            A, BB, pa, pb);
    pair_kernel<<<dim3(NN / 128, NN / 128), 512, 0, stream>>>(
        A, BB, pa, pb, W2, b2, out);
}